// Round 1
// baseline (359.799 us; speedup 1.0000x reference)
//
#include <hip/hip_runtime.h>
#include <math.h>

typedef unsigned short u16;
typedef unsigned int u32;
typedef __attribute__((ext_vector_type(8))) __bf16 bf16x8;
typedef __attribute__((ext_vector_type(4))) float f32x4;
typedef __attribute__((ext_vector_type(8))) unsigned short u16x8;

__device__ __forceinline__ u16 f2bf(float f) {
    u32 u = __builtin_bit_cast(u32, f);
    u32 r = (u + 0x7fffu + ((u >> 16) & 1u)) >> 16;
    return (u16)r;
}
__device__ __forceinline__ float bf2f(u16 h) {
    return __builtin_bit_cast(float, (u32)h << 16);
}

#define GL16(gp, lp) __builtin_amdgcn_global_load_lds( \
    (const __attribute__((address_space(1))) u32*)(gp), \
    (__attribute__((address_space(3))) u32*)(lp), 16, 0, 0)

// ---------------------------------------------------------------------------
// fp32 -> bf16 convert (vectorized, 8 elems/thread)
__global__ __launch_bounds__(256) void f2bker(const float* __restrict__ in, u16* __restrict__ out) {
    size_t i = ((size_t)blockIdx.x * 256 + threadIdx.x) * 8;
    float4 a = *(const float4*)(in + i);
    float4 b = *(const float4*)(in + i + 4);
    u16x8 w;
    w[0] = f2bf(a.x); w[1] = f2bf(a.y); w[2] = f2bf(a.z); w[3] = f2bf(a.w);
    w[4] = f2bf(b.x); w[5] = f2bf(b.y); w[6] = f2bf(b.z); w[7] = f2bf(b.w);
    *(u16x8*)(out + i) = w;
}

// ---------------------------------------------------------------------------
// transpose + convert: in fp32 [R][C] -> out bf16 [C][R]  (64x64 tiles)
__global__ __launch_bounds__(256) void wtrans(const float* __restrict__ in, u16* __restrict__ out,
                                              int R, int C) {
    __shared__ u16 t[64 * 65];
    const int tid = threadIdx.x;
    const int c0 = blockIdx.x * 64, r0 = blockIdx.y * 64;
#pragma unroll
    for (int it = 0; it < 4; ++it) {
        int f = it * 256 + tid;
        int row = f >> 4, c4 = (f & 15) * 4;
        float4 v = *(const float4*)(in + (size_t)(r0 + row) * C + c0 + c4);
        t[row * 65 + c4 + 0] = f2bf(v.x);
        t[row * 65 + c4 + 1] = f2bf(v.y);
        t[row * 65 + c4 + 2] = f2bf(v.z);
        t[row * 65 + c4 + 3] = f2bf(v.w);
    }
    __syncthreads();
#pragma unroll
    for (int it = 0; it < 2; ++it) {
        int f = it * 256 + tid;
        int oc = f >> 3, r8 = (f & 7) * 8;
        u16x8 w;
#pragma unroll
        for (int j = 0; j < 8; ++j) w[j] = t[(r8 + j) * 65 + oc];
        *(u16x8*)(out + (size_t)(c0 + oc) * R + r0 + r8) = w;
    }
}

// ---------------------------------------------------------------------------
// V (B,H,T,D) bf16 -> VbT (B,H,D,T) bf16, per-bh 64x64 tiles over T
__global__ __launch_bounds__(256) void vtrans(const u16* __restrict__ Vb, u16* __restrict__ VbT) {
    __shared__ u16 t[64 * 65];
    const int tid = threadIdx.x;
    const int t0 = blockIdx.x * 64;
    const size_t bh = blockIdx.y;
#pragma unroll
    for (int it = 0; it < 2; ++it) {
        int f = it * 256 + tid;
        int row = f >> 3, c8 = (f & 7) * 8;
        u16x8 v = *(const u16x8*)(Vb + (bh * 2048 + t0 + row) * 64 + c8);
#pragma unroll
        for (int j = 0; j < 8; ++j) t[row * 65 + c8 + j] = v[j];
    }
    __syncthreads();
#pragma unroll
    for (int it = 0; it < 2; ++it) {
        int f = it * 256 + tid;
        int d = f >> 3, r8 = (f & 7) * 8;
        u16x8 w;
#pragma unroll
        for (int j = 0; j < 8; ++j) w[j] = t[(r8 + j) * 65 + d];
        *(u16x8*)(VbT + (bh * 64 + d) * 2048 + t0 + r8) = w;
    }
}

// ---------------------------------------------------------------------------
// RoPE table: tab[t][d2] = (cos(t*invf), sin(t*invf)), T=2048, 32 pairs
__global__ __launch_bounds__(256) void rope_tab(float2* __restrict__ tab) {
    int i = blockIdx.x * 256 + threadIdx.x;   // 65536
    int tpos = i >> 5, d2 = i & 31;
    float invf = powf(10000.f, -(float)(2 * d2) / 64.f);
    float fr = (float)tpos * invf;
    tab[i] = make_float2(cosf(fr), sinf(fr));
}

// RoPE in-place on Q or K (B,H,T,D) bf16; pair index i over all elems/2
__global__ __launch_bounds__(256) void rope_ip(u16* __restrict__ Q, u16* __restrict__ K,
                                               const float2* __restrict__ tab) {
    int i = blockIdx.x * 256 + threadIdx.x;   // 4,194,304 pairs
    u32* p = (u32*)(blockIdx.y ? K : Q) + i;
    int d2 = i & 31, tpos = (i >> 5) & 2047;
    float2 cs = tab[tpos * 32 + d2];
    u32 v = *p;
    float xe = bf2f((u16)(v & 0xffff));
    float xo = bf2f((u16)(v >> 16));
    float re = xe * cs.x - xo * cs.y;
    float ro = xe * cs.y + xo * cs.x;
    *p = (u32)f2bf(re) | ((u32)f2bf(ro) << 16);
}

// ---------------------------------------------------------------------------
// GEMM: C[MxN] = A[MxK](bf16,rowmajor) * Bt[NxK](bf16,rowmajor-as-B^T) + bias
// 128x128 tile, BK=32, 256 threads (2x2 waves, 64x64 each), m97 structure.
// MODE 0: fp32 out. MODE 1: scatter qkv to (B,H,T,D) bf16.
template <int MODE>
__global__ __launch_bounds__(256, 2) void gemm_bt(
    const u16* __restrict__ A, const u16* __restrict__ Bt,
    const float* __restrict__ bias, float* __restrict__ Cf,
    u16* __restrict__ Qb, u16* __restrict__ Kb, u16* __restrict__ Vb,
    int M, int N, int K) {
    __shared__ __align__(16) u16 lsA[128 * 32];
    __shared__ __align__(16) u16 lsB[128 * 32];
    const int tid = threadIdx.x;
    const int wv = tid >> 6, lane = tid & 63;
    const int g = lane >> 4, c = lane & 15;
    const int m0 = blockIdx.y * 128, n0 = blockIdx.x * 128;
    const int wr = wv >> 1, wc = wv & 1;

    f32x4 acc[4][4] = {};

    const u16* gA = A + (size_t)(m0 + (tid >> 2)) * K + (tid & 3) * 8;
    const u16* gB = Bt + (size_t)(n0 + (tid >> 2)) * K + (tid & 3) * 8;
    const size_t rs64 = (size_t)64 * K;
    unsigned ldsW = (unsigned)__builtin_amdgcn_readfirstlane(wv * 1024);
    char* lA = (char*)lsA + ldsW;
    char* lB = (char*)lsB + ldsW;

    for (int k0 = 0; k0 < K; k0 += 32) {
        GL16(gA + k0, lA);
        GL16(gA + k0 + rs64, lA + 4096);
        GL16(gB + k0, lB);
        GL16(gB + k0 + rs64, lB + 4096);
        __syncthreads();
        bf16x8 af[4], bfr[4];
#pragma unroll
        for (int i = 0; i < 4; ++i)
            af[i] = *(const bf16x8*)(lsA + (wr * 64 + i * 16 + c) * 32 + g * 8);
#pragma unroll
        for (int j = 0; j < 4; ++j)
            bfr[j] = *(const bf16x8*)(lsB + (wc * 64 + j * 16 + c) * 32 + g * 8);
#pragma unroll
        for (int i = 0; i < 4; ++i)
#pragma unroll
            for (int j = 0; j < 4; ++j)
                acc[i][j] = __builtin_amdgcn_mfma_f32_16x16x32_bf16(af[i], bfr[j], acc[i][j], 0, 0, 0);
        __syncthreads();
    }

    if (MODE == 0) {
#pragma unroll
        for (int i = 0; i < 4; ++i)
#pragma unroll
            for (int r = 0; r < 4; ++r) {
                int m = m0 + wr * 64 + i * 16 + g * 4 + r;
#pragma unroll
                for (int j = 0; j < 4; ++j) {
                    int n = n0 + wc * 64 + j * 16 + c;
                    Cf[(size_t)m * N + n] = acc[i][j][r] + bias[n];
                }
            }
    } else {
        const int part = n0 >> 10;  // tile never crosses 1024-boundary
        u16* dst = (part == 0) ? Qb : ((part == 1) ? Kb : Vb);
#pragma unroll
        for (int i = 0; i < 4; ++i)
#pragma unroll
            for (int r = 0; r < 4; ++r) {
                int m = m0 + wr * 64 + i * 16 + g * 4 + r;
                int b = m >> 11, t = m & 2047;
#pragma unroll
                for (int j = 0; j < 4; ++j) {
                    int n = n0 + wc * 64 + j * 16 + c;
                    int e = n & 1023, h = e >> 6, d = e & 63;
                    float v = acc[i][j][r] + bias[n];
                    dst[(((size_t)b * 16 + h) * 2048 + t) * 64 + d] = f2bf(v);
                }
            }
    }
}

// ---------------------------------------------------------------------------
// Flash attention: grid (T/64, B*H), 256 threads (4 waves x 16 q-rows).
// Q,K: (B,H,T,D) bf16 (roped). VbT: (B,H,D,T) bf16. Ob: (B,T,E) bf16.
__global__ __launch_bounds__(256, 2) void attn_fwd(
    const u16* __restrict__ Qb, const u16* __restrict__ Kb,
    const u16* __restrict__ VbT, u16* __restrict__ Ob) {
    __shared__ __align__(16) u16 Kt[4096];   // [kv=64][d=64], XOR-swizzled
    __shared__ __align__(16) u16 Vt[4096];   // [d=64][kv=64], XOR-swizzled
    __shared__ __align__(16) u16 Pt[4][1024];  // per-wave [q=16][kv=64], swizzled
    const int tid = threadIdx.x, wv = tid >> 6, lane = tid & 63;
    const int g = lane >> 4, c = lane & 15;
    const int qt = blockIdx.x, bh = blockIdx.y;
    const int b = bh >> 4, h = bh & 15;
    const int q0 = qt * 64;

    const u16* qp = Qb + ((size_t)bh * 2048 + q0 + wv * 16 + c) * 64 + g * 8;
    bf16x8 aq0 = *(const bf16x8*)(qp);
    bf16x8 aq1 = *(const bf16x8*)(qp + 32);

    float m_r[4] = {-INFINITY, -INFINITY, -INFINITY, -INFINITY};
    float l_r[4] = {0.f, 0.f, 0.f, 0.f};
    f32x4 accO[4] = {};

    const int stRow = tid >> 3;
    const int stCol = (tid & 7) * 8;
    const u16* gK = Kb + (size_t)bh * 2048 * 64;
    const u16* gV = VbT + (size_t)bh * 64 * 2048;
    char* pw = (char*)&Pt[wv][0];

    for (int kt = 0; kt <= qt; ++kt) {
#pragma unroll
        for (int it = 0; it < 2; ++it) {
            int row = stRow + it * 32;
            unsigned ad = ((unsigned)(row * 128 + stCol * 2)) ^ ((unsigned)(row & 7) << 4);
            u16x8 kvv = *(const u16x8*)(gK + (size_t)(kt * 64 + row) * 64 + stCol);
            *(u16x8*)((char*)Kt + ad) = kvv;
            u16x8 vvv = *(const u16x8*)(gV + (size_t)row * 2048 + kt * 64 + stCol);
            *(u16x8*)((char*)Vt + ad) = vvv;
        }
        __syncthreads();

        // S = Q K^T  (16q x 64kv per wave)
        f32x4 s[4] = {};
#pragma unroll
        for (int j = 0; j < 4; ++j) {
            int kv = j * 16 + c;
            unsigned sw = (unsigned)(kv & 7) << 4;
            unsigned base = (unsigned)(kv * 128 + g * 16);
            bf16x8 b0 = *(const bf16x8*)((char*)Kt + (base ^ sw));
            bf16x8 b1 = *(const bf16x8*)((char*)Kt + ((base + 64) ^ sw));
            s[j] = __builtin_amdgcn_mfma_f32_16x16x32_bf16(aq0, b0, s[j], 0, 0, 0);
            s[j] = __builtin_amdgcn_mfma_f32_16x16x32_bf16(aq1, b1, s[j], 0, 0, 0);
        }

        const bool diag = (kt == qt);
#pragma unroll
        for (int r = 0; r < 4; ++r) {
            int qg = q0 + wv * 16 + g * 4 + r;
            float mx = -INFINITY;
#pragma unroll
            for (int j = 0; j < 4; ++j) {
                float v = s[j][r] * 0.125f;
                if (diag && (kt * 64 + j * 16 + c) > qg) v = -INFINITY;
                s[j][r] = v;
                mx = fmaxf(mx, v);
            }
#pragma unroll
            for (int off = 1; off < 16; off <<= 1) mx = fmaxf(mx, __shfl_xor(mx, off));
            float mnew = fmaxf(m_r[r], mx);
            float alpha = __expf(m_r[r] - mnew);
            float sum = 0.f;
#pragma unroll
            for (int j = 0; j < 4; ++j) {
                float p = __expf(s[j][r] - mnew);
                s[j][r] = p;
                sum += p;
            }
#pragma unroll
            for (int off = 1; off < 16; off <<= 1) sum += __shfl_xor(sum, off);
            l_r[r] = l_r[r] * alpha + sum;
            m_r[r] = mnew;
#pragma unroll
            for (int dj = 0; dj < 4; ++dj) accO[dj][r] *= alpha;
        }

        // P -> LDS (bf16, swizzled); same-wave buffer, no barrier needed
#pragma unroll
        for (int r = 0; r < 4; ++r) {
            int prow = g * 4 + r;
            unsigned swp = (unsigned)(prow & 7) << 4;
#pragma unroll
            for (int j = 0; j < 4; ++j) {
                unsigned ad = ((unsigned)(prow * 128 + (j * 16 + c) * 2)) ^ swp;
                *(u16*)(pw + ad) = f2bf(s[j][r]);
            }
        }

        // O += P V
#pragma unroll
        for (int ks = 0; ks < 2; ++ks) {
            unsigned pb = ((unsigned)(c * 128 + g * 16 + ks * 64)) ^ ((unsigned)(c & 7) << 4);
            bf16x8 pa = *(const bf16x8*)(pw + pb);
#pragma unroll
            for (int dj = 0; dj < 4; ++dj) {
                int d = dj * 16 + c;
                unsigned vb = ((unsigned)(d * 128 + g * 16 + ks * 64)) ^ ((unsigned)(d & 7) << 4);
                bf16x8 bv = *(const bf16x8*)((char*)Vt + vb);
                accO[dj] = __builtin_amdgcn_mfma_f32_16x16x32_bf16(pa, bv, accO[dj], 0, 0, 0);
            }
        }
        __syncthreads();
    }

#pragma unroll
    for (int r = 0; r < 4; ++r) {
        float inv = 1.f / l_r[r];
        int t = q0 + wv * 16 + g * 4 + r;
#pragma unroll
        for (int dj = 0; dj < 4; ++dj) {
            float o = accO[dj][r] * inv;
            Ob[((size_t)b * 2048 + t) * 1024 + h * 64 + dj * 16 + c] = f2bf(o);
        }
    }
}

// ---------------------------------------------------------------------------
extern "C" void kernel_launch(void* const* d_in, const int* in_sizes, int n_in,
                              void* d_out, int out_size, void* d_ws, size_t ws_size,
                              hipStream_t stream) {
    const float* x = (const float*)d_in[0];
    const float* Wqkv = (const float*)d_in[1];
    const float* bqkv = (const float*)d_in[2];
    const float* Wproj = (const float*)d_in[3];
    const float* bproj = (const float*)d_in[4];
    float* out = (float*)d_out;

    char* ws = (char*)d_ws;
    u16* xb = (u16*)(ws);                       // 16,777,216 B; reused as Ob
    u16* WqkvT = (u16*)(ws + 16777216);         //  6,291,456 B
    u16* WprojT = (u16*)(ws + 23068672);        //  2,097,152 B
    u16* Qb = (u16*)(ws + 25165824);            // 16,777,216 B
    u16* Kb = (u16*)(ws + 41943040);            // 16,777,216 B
    u16* Vb = (u16*)(ws + 58720256);            // 16,777,216 B
    u16* VbT = (u16*)(ws + 75497472);           // 16,777,216 B
    float2* tab = (float2*)(ws + 92274688);     //    524,288 B  (total ~92.8 MB)

    f2bker<<<4096, 256, 0, stream>>>(x, xb);
    wtrans<<<dim3(48, 16), 256, 0, stream>>>(Wqkv, WqkvT, 1024, 3072);
    wtrans<<<dim3(16, 16), 256, 0, stream>>>(Wproj, WprojT, 1024, 1024);
    rope_tab<<<256, 256, 0, stream>>>(tab);
    gemm_bt<1><<<dim3(24, 64), 256, 0, stream>>>(xb, WqkvT, bqkv, nullptr, Qb, Kb, Vb,
                                                 8192, 3072, 1024);
    rope_ip<<<dim3(16384, 2), 256, 0, stream>>>(Qb, Kb, tab);
    vtrans<<<dim3(32, 64), 256, 0, stream>>>(Vb, VbT);
    attn_fwd<<<dim3(32, 64), 256, 0, stream>>>(Qb, Kb, VbT, xb /*Ob*/);
    gemm_bt<0><<<dim3(8, 64), 256, 0, stream>>>(xb, WprojT, bproj, out,
                                                nullptr, nullptr, nullptr,
                                                8192, 1024, 1024);
}

// Round 2
// 264.478 us; speedup vs baseline: 1.3604x; 1.3604x over previous
//
#include <hip/hip_runtime.h>
#include <math.h>

typedef unsigned short u16;
typedef unsigned int u32;
typedef __attribute__((ext_vector_type(8))) __bf16 bf16x8;
typedef __attribute__((ext_vector_type(4))) float f32x4;
typedef __attribute__((ext_vector_type(8))) unsigned short u16x8;

__device__ __forceinline__ u16 f2bf(float f) {
    u32 u = __builtin_bit_cast(u32, f);
    u32 r = (u + 0x7fffu + ((u >> 16) & 1u)) >> 16;
    return (u16)r;
}
__device__ __forceinline__ float bf2f(u16 h) {
    return __builtin_bit_cast(float, (u32)h << 16);
}

#define GL16(gp, lp) __builtin_amdgcn_global_load_lds( \
    (const __attribute__((address_space(1))) u32*)(gp), \
    (__attribute__((address_space(3))) u32*)(lp), 16, 0, 0)

// ---------------------------------------------------------------------------
// fp32 -> bf16 convert (vectorized, 8 elems/thread)
__global__ __launch_bounds__(256) void f2bker(const float* __restrict__ in, u16* __restrict__ out) {
    size_t i = ((size_t)blockIdx.x * 256 + threadIdx.x) * 8;
    float4 a = *(const float4*)(in + i);
    float4 b = *(const float4*)(in + i + 4);
    u16x8 w;
    w[0] = f2bf(a.x); w[1] = f2bf(a.y); w[2] = f2bf(a.z); w[3] = f2bf(a.w);
    w[4] = f2bf(b.x); w[5] = f2bf(b.y); w[6] = f2bf(b.z); w[7] = f2bf(b.w);
    *(u16x8*)(out + i) = w;
}

// ---------------------------------------------------------------------------
// transpose + convert: in fp32 [R][C] -> out bf16 [C][R]  (64x64 tiles)
__global__ __launch_bounds__(256) void wtrans(const float* __restrict__ in, u16* __restrict__ out,
                                              int R, int C) {
    __shared__ u16 t[64 * 65];
    const int tid = threadIdx.x;
    const int c0 = blockIdx.x * 64, r0 = blockIdx.y * 64;
#pragma unroll
    for (int it = 0; it < 4; ++it) {
        int f = it * 256 + tid;
        int row = f >> 4, c4 = (f & 15) * 4;
        float4 v = *(const float4*)(in + (size_t)(r0 + row) * C + c0 + c4);
        t[row * 65 + c4 + 0] = f2bf(v.x);
        t[row * 65 + c4 + 1] = f2bf(v.y);
        t[row * 65 + c4 + 2] = f2bf(v.z);
        t[row * 65 + c4 + 3] = f2bf(v.w);
    }
    __syncthreads();
#pragma unroll
    for (int it = 0; it < 2; ++it) {
        int f = it * 256 + tid;
        int oc = f >> 3, r8 = (f & 7) * 8;
        u16x8 w;
#pragma unroll
        for (int j = 0; j < 8; ++j) w[j] = t[(r8 + j) * 65 + oc];
        *(u16x8*)(out + (size_t)(c0 + oc) * R + r0 + r8) = w;
    }
}

// ---------------------------------------------------------------------------
// V (B,H,T,D) bf16 -> VbT (B,H,D,T) bf16, per-bh 64x64 tiles over T
__global__ __launch_bounds__(256) void vtrans(const u16* __restrict__ Vb, u16* __restrict__ VbT) {
    __shared__ u16 t[64 * 65];
    const int tid = threadIdx.x;
    const int t0 = blockIdx.x * 64;
    const size_t bh = blockIdx.y;
#pragma unroll
    for (int it = 0; it < 2; ++it) {
        int f = it * 256 + tid;
        int row = f >> 3, c8 = (f & 7) * 8;
        u16x8 v = *(const u16x8*)(Vb + (bh * 2048 + t0 + row) * 64 + c8);
#pragma unroll
        for (int j = 0; j < 8; ++j) t[row * 65 + c8 + j] = v[j];
    }
    __syncthreads();
#pragma unroll
    for (int it = 0; it < 2; ++it) {
        int f = it * 256 + tid;
        int d = f >> 3, r8 = (f & 7) * 8;
        u16x8 w;
#pragma unroll
        for (int j = 0; j < 8; ++j) w[j] = t[(r8 + j) * 65 + d];
        *(u16x8*)(VbT + (bh * 64 + d) * 2048 + t0 + r8) = w;
    }
}

// ---------------------------------------------------------------------------
// RoPE table: tab[t][d2] = (cos(t*invf), sin(t*invf)), T=2048, 32 pairs
__global__ __launch_bounds__(256) void rope_tab(float2* __restrict__ tab) {
    int i = blockIdx.x * 256 + threadIdx.x;   // 65536
    int tpos = i >> 5, d2 = i & 31;
    float invf = powf(10000.f, -(float)(2 * d2) / 64.f);
    float fr = (float)tpos * invf;
    tab[i] = make_float2(cosf(fr), sinf(fr));
}

// RoPE in-place on Q or K (B,H,T,D) bf16; pair index i over all elems/2
__global__ __launch_bounds__(256) void rope_ip(u16* __restrict__ Q, u16* __restrict__ K,
                                               const float2* __restrict__ tab) {
    int i = blockIdx.x * 256 + threadIdx.x;   // 4,194,304 pairs
    u32* p = (u32*)(blockIdx.y ? K : Q) + i;
    int d2 = i & 31, tpos = (i >> 5) & 2047;
    float2 cs = tab[tpos * 32 + d2];
    u32 v = *p;
    float xe = bf2f((u16)(v & 0xffff));
    float xo = bf2f((u16)(v >> 16));
    float re = xe * cs.x - xo * cs.y;
    float ro = xe * cs.y + xo * cs.x;
    *p = (u32)f2bf(re) | ((u32)f2bf(ro) << 16);
}

// ---------------------------------------------------------------------------
// GEMM: C[MxN] = A[MxK](bf16,rowmajor) * Bt[NxK](bf16,rowmajor-as-B^T) + bias
// 128x128 tile, BK=32, 256 threads (2x2 waves, 64x64 each), m97 structure.
// MODE 0: fp32 out. MODE 1: scatter qkv to (B,H,T,D) bf16.
template <int MODE>
__global__ __launch_bounds__(256, 2) void gemm_bt(
    const u16* __restrict__ A, const u16* __restrict__ Bt,
    const float* __restrict__ bias, float* __restrict__ Cf,
    u16* __restrict__ Qb, u16* __restrict__ Kb, u16* __restrict__ Vb,
    int M, int N, int K) {
    __shared__ __align__(16) u16 lsA[128 * 32];
    __shared__ __align__(16) u16 lsB[128 * 32];
    const int tid = threadIdx.x;
    const int wv = tid >> 6, lane = tid & 63;
    const int g = lane >> 4, c = lane & 15;
    const int m0 = blockIdx.y * 128, n0 = blockIdx.x * 128;
    const int wr = wv >> 1, wc = wv & 1;

    f32x4 acc[4][4] = {};

    const u16* gA = A + (size_t)(m0 + (tid >> 2)) * K + (tid & 3) * 8;
    const u16* gB = Bt + (size_t)(n0 + (tid >> 2)) * K + (tid & 3) * 8;
    const size_t rs64 = (size_t)64 * K;
    unsigned ldsW = (unsigned)__builtin_amdgcn_readfirstlane(wv * 1024);
    char* lA = (char*)lsA + ldsW;
    char* lB = (char*)lsB + ldsW;

    for (int k0 = 0; k0 < K; k0 += 32) {
        GL16(gA + k0, lA);
        GL16(gA + k0 + rs64, lA + 4096);
        GL16(gB + k0, lB);
        GL16(gB + k0 + rs64, lB + 4096);
        __syncthreads();
        bf16x8 af[4], bfr[4];
#pragma unroll
        for (int i = 0; i < 4; ++i)
            af[i] = *(const bf16x8*)(lsA + (wr * 64 + i * 16 + c) * 32 + g * 8);
#pragma unroll
        for (int j = 0; j < 4; ++j)
            bfr[j] = *(const bf16x8*)(lsB + (wc * 64 + j * 16 + c) * 32 + g * 8);
#pragma unroll
        for (int i = 0; i < 4; ++i)
#pragma unroll
            for (int j = 0; j < 4; ++j)
                acc[i][j] = __builtin_amdgcn_mfma_f32_16x16x32_bf16(af[i], bfr[j], acc[i][j], 0, 0, 0);
        __syncthreads();
    }

    if (MODE == 0) {
#pragma unroll
        for (int i = 0; i < 4; ++i)
#pragma unroll
            for (int r = 0; r < 4; ++r) {
                int m = m0 + wr * 64 + i * 16 + g * 4 + r;
#pragma unroll
                for (int j = 0; j < 4; ++j) {
                    int n = n0 + wc * 64 + j * 16 + c;
                    Cf[(size_t)m * N + n] = acc[i][j][r] + bias[n];
                }
            }
    } else {
        const int part = n0 >> 10;  // tile never crosses 1024-boundary
        u16* dst = (part == 0) ? Qb : ((part == 1) ? Kb : Vb);
#pragma unroll
        for (int i = 0; i < 4; ++i)
#pragma unroll
            for (int r = 0; r < 4; ++r) {
                int m = m0 + wr * 64 + i * 16 + g * 4 + r;
                int b = m >> 11, t = m & 2047;
#pragma unroll
                for (int j = 0; j < 4; ++j) {
                    int n = n0 + wc * 64 + j * 16 + c;
                    int e = n & 1023, h = e >> 6, d = e & 63;
                    float v = acc[i][j][r] + bias[n];
                    dst[(((size_t)b * 16 + h) * 2048 + t) * 64 + d] = f2bf(v);
                }
            }
    }
}

// ---------------------------------------------------------------------------
// Flash attention, swapped-operand form. grid (T/64, B*H), 256 threads
// (4 waves x 16 q each). Per wave, per kv-tile (64):
//   S^T = mfma(A=K, B=Q)   -> lane owns q=c, 16 kv values in regs
//   softmax in-lane (15 fmax + 2 shfl_xor), P stays lane-local
//   O^T += mfma(A=V^T, B=P^T) -> col=q=c, so alpha/l stay in-lane
// K/V double-buffered in LDS (XOR swizzle), ONE barrier per tile; next tile's
// global loads issued right after the barrier (T14) so HBM latency hides
// under QK^T+softmax+PV.
__global__ __launch_bounds__(256, 4) void attn_fwd(
    const u16* __restrict__ Qb, const u16* __restrict__ Kb,
    const u16* __restrict__ VbT, u16* __restrict__ Ob) {
    __shared__ __align__(16) u16 Kt[2][4096];   // [buf][kv=64][d=64] swizzled
    __shared__ __align__(16) u16 Vt[2][4096];   // [buf][d=64][kv=64] swizzled
    __shared__ __align__(16) u16 Pt[4][1024];   // per-wave [q=16][kv=64] swizzled
    const int tid = threadIdx.x, wv = tid >> 6, lane = tid & 63;
    const int g = lane >> 4, c = lane & 15;
    const int qt = 31 - blockIdx.x;             // longest blocks first
    const int bh = blockIdx.y;
    const int b = bh >> 4, h = bh & 15;
    const int q0 = qt * 64;
    const int qg = q0 + wv * 16 + c;            // this lane's q row

    // Q fragment (B-operand): Q[q=c][d = g*8 + i], two 32-wide d chunks
    const u16* qp = Qb + ((size_t)bh * 2048 + qg) * 64 + g * 8;
    bf16x8 bq0 = *(const bf16x8*)(qp);
    bf16x8 bq1 = *(const bf16x8*)(qp + 32);

    float m_r = -INFINITY, l_r = 0.f;
    f32x4 accO[4] = {};                         // O^T: row d=dj*16+4g+r, col q=c

    const int stRow = tid >> 3;                 // 0..31
    const int stCol = (tid & 7) * 8;            // 0..56
    const u16* gK = Kb + (size_t)bh * 2048 * 64 + (size_t)stRow * 64 + stCol;
    const u16* gV = VbT + (size_t)bh * 64 * 2048 + (size_t)stRow * 2048 + stCol;
    const unsigned sw8 = (unsigned)(stRow & 7) << 4;
    const unsigned sAd0 = ((unsigned)(stRow * 128 + stCol * 2)) ^ sw8;
    const unsigned sAd1 = ((unsigned)((stRow + 32) * 128 + stCol * 2)) ^ sw8;
    const unsigned swz = (unsigned)(c & 7) << 4;
    char* pw = (char*)&Pt[wv][0];

    // prologue: stage tile 0
    u16x8 kr0 = *(const u16x8*)(gK);
    u16x8 kr1 = *(const u16x8*)(gK + 32 * 64);
    u16x8 vr0 = *(const u16x8*)(gV);
    u16x8 vr1 = *(const u16x8*)(gV + 32 * 2048);
    *(u16x8*)((char*)Kt[0] + sAd0) = kr0;
    *(u16x8*)((char*)Kt[0] + sAd1) = kr1;
    *(u16x8*)((char*)Vt[0] + sAd0) = vr0;
    *(u16x8*)((char*)Vt[0] + sAd1) = vr1;
    int cur = 0;

    for (int kt = 0; kt <= qt; ++kt) {
        __syncthreads();                        // buf[cur] ready for all waves
        if (kt < qt) {                          // issue next tile early (T14)
            const u16* nK = gK + (size_t)(kt + 1) * 64 * 64;
            const u16* nV = gV + (size_t)(kt + 1) * 64;
            kr0 = *(const u16x8*)(nK);
            kr1 = *(const u16x8*)(nK + 32 * 64);
            vr0 = *(const u16x8*)(nV);
            vr1 = *(const u16x8*)(nV + 32 * 2048);
        }
        const char* Kc = (const char*)Kt[cur];
        const char* Vc = (const char*)Vt[cur];

        // S^T = K x Q^T : 4 kv-subtiles x 2 d-chunks
        f32x4 s[4] = {};
#pragma unroll
        for (int j = 0; j < 4; ++j) {
            unsigned rb = (unsigned)((16 * j + c) * 128 + g * 16);
            bf16x8 ka0 = *(const bf16x8*)(Kc + (rb ^ swz));
            bf16x8 ka1 = *(const bf16x8*)(Kc + ((rb + 64) ^ swz));
            s[j] = __builtin_amdgcn_mfma_f32_16x16x32_bf16(ka0, bq0, s[j], 0, 0, 0);
            s[j] = __builtin_amdgcn_mfma_f32_16x16x32_bf16(ka1, bq1, s[j], 0, 0, 0);
        }

        // online softmax: lane owns q=c, kv = kt*64 + 16j + 4g + r
        const bool diag = (kt == qt);
        float sv[16];
        float mx = -INFINITY;
#pragma unroll
        for (int j = 0; j < 4; ++j)
#pragma unroll
            for (int r = 0; r < 4; ++r) {
                float v = s[j][r] * 0.125f;
                if (diag && (kt * 64 + j * 16 + 4 * g + r) > qg) v = -INFINITY;
                sv[j * 4 + r] = v;
                mx = fmaxf(mx, v);
            }
        mx = fmaxf(mx, __shfl_xor(mx, 16));
        mx = fmaxf(mx, __shfl_xor(mx, 32));
        float mnew = fmaxf(m_r, mx);
        float alpha = __expf(m_r - mnew);
        float sum = 0.f;
        u32 pp[8];
#pragma unroll
        for (int jt = 0; jt < 8; ++jt) {
            float p0 = __expf(sv[jt * 2] - mnew);
            float p1 = __expf(sv[jt * 2 + 1] - mnew);
            sum += p0 + p1;
            pp[jt] = (u32)f2bf(p0) | ((u32)f2bf(p1) << 16);
        }
        sum += __shfl_xor(sum, 16);
        sum += __shfl_xor(sum, 32);
        m_r = mnew;
        l_r = l_r * alpha + sum;
#pragma unroll
        for (int dj = 0; dj < 4; ++dj) accO[dj] *= alpha;

        // P^T -> per-wave LDS (packed bf16 pairs), same wave, no barrier
#pragma unroll
        for (int j = 0; j < 4; ++j) {
            unsigned base = (unsigned)(c * 128 + j * 32 + g * 8);
            uint2 w2;
            w2.x = pp[j * 2];
            w2.y = pp[j * 2 + 1];
            *(uint2*)(pw + (base ^ swz)) = w2;
        }

        // O^T += V^T x P^T
#pragma unroll
        for (int ks = 0; ks < 2; ++ks) {
            bf16x8 pb = *(const bf16x8*)(pw + ((unsigned)(c * 128 + ks * 64 + g * 16) ^ swz));
#pragma unroll
            for (int dj = 0; dj < 4; ++dj) {
                unsigned vb = (unsigned)((dj * 16 + c) * 128 + ks * 64 + g * 16) ^ swz;
                bf16x8 va = *(const bf16x8*)(Vc + vb);
                accO[dj] = __builtin_amdgcn_mfma_f32_16x16x32_bf16(va, pb, accO[dj], 0, 0, 0);
            }
        }

        // stage next tile into the other buffer (vmcnt drain lands here)
        if (kt < qt) {
            int nb = cur ^ 1;
            *(u16x8*)((char*)Kt[nb] + sAd0) = kr0;
            *(u16x8*)((char*)Kt[nb] + sAd1) = kr1;
            *(u16x8*)((char*)Vt[nb] + sAd0) = vr0;
            *(u16x8*)((char*)Vt[nb] + sAd1) = vr1;
            cur = nb;
        }
    }

    // epilogue: O[q][d] = accO^T / l, write bf16 pairs (8B per dj)
    float inv = 1.f / l_r;
    u16* ob = Ob + ((size_t)b * 2048 + qg) * 1024 + h * 64;
#pragma unroll
    for (int dj = 0; dj < 4; ++dj) {
        f32x4 o = accO[dj] * inv;
        uint2 w;
        w.x = (u32)f2bf(o[0]) | ((u32)f2bf(o[1]) << 16);
        w.y = (u32)f2bf(o[2]) | ((u32)f2bf(o[3]) << 16);
        *(uint2*)(ob + dj * 16 + 4 * g) = w;
    }
}

// ---------------------------------------------------------------------------
extern "C" void kernel_launch(void* const* d_in, const int* in_sizes, int n_in,
                              void* d_out, int out_size, void* d_ws, size_t ws_size,
                              hipStream_t stream) {
    const float* x = (const float*)d_in[0];
    const float* Wqkv = (const float*)d_in[1];
    const float* bqkv = (const float*)d_in[2];
    const float* Wproj = (const float*)d_in[3];
    const float* bproj = (const float*)d_in[4];
    float* out = (float*)d_out;

    char* ws = (char*)d_ws;
    u16* xb = (u16*)(ws);                       // 16,777,216 B; reused as Ob
    u16* WqkvT = (u16*)(ws + 16777216);         //  6,291,456 B
    u16* WprojT = (u16*)(ws + 23068672);        //  2,097,152 B
    u16* Qb = (u16*)(ws + 25165824);            // 16,777,216 B
    u16* Kb = (u16*)(ws + 41943040);            // 16,777,216 B
    u16* Vb = (u16*)(ws + 58720256);            // 16,777,216 B
    u16* VbT = (u16*)(ws + 75497472);           // 16,777,216 B
    float2* tab = (float2*)(ws + 92274688);     //    524,288 B  (total ~92.8 MB)

    f2bker<<<4096, 256, 0, stream>>>(x, xb);
    wtrans<<<dim3(48, 16), 256, 0, stream>>>(Wqkv, WqkvT, 1024, 3072);
    wtrans<<<dim3(16, 16), 256, 0, stream>>>(Wproj, WprojT, 1024, 1024);
    rope_tab<<<256, 256, 0, stream>>>(tab);
    gemm_bt<1><<<dim3(24, 64), 256, 0, stream>>>(xb, WqkvT, bqkv, nullptr, Qb, Kb, Vb,
                                                 8192, 3072, 1024);
    rope_ip<<<dim3(16384, 2), 256, 0, stream>>>(Qb, Kb, tab);
    vtrans<<<dim3(32, 64), 256, 0, stream>>>(Vb, VbT);
    attn_fwd<<<dim3(32, 64), 256, 0, stream>>>(Qb, Kb, VbT, xb /*Ob*/);
    gemm_bt<0><<<dim3(8, 64), 256, 0, stream>>>(xb, WprojT, bproj, out,
                                                nullptr, nullptr, nullptr,
                                                8192, 1024, 1024);
}

// Round 3
// 238.534 us; speedup vs baseline: 1.5084x; 1.1088x over previous
//
#include <hip/hip_runtime.h>
#include <math.h>

typedef unsigned short u16;
typedef unsigned int u32;
typedef __attribute__((ext_vector_type(8))) __bf16 bf16x8;
typedef __attribute__((ext_vector_type(4))) float f32x4;
typedef __attribute__((ext_vector_type(8))) unsigned short u16x8;

__device__ __forceinline__ u16 f2bf(float f) {
    u32 u = __builtin_bit_cast(u32, f);
    u32 r = (u + 0x7fffu + ((u >> 16) & 1u)) >> 16;
    return (u16)r;
}
__device__ __forceinline__ float bf2f(u16 h) {
    return __builtin_bit_cast(float, (u32)h << 16);
}
__device__ __forceinline__ float exp2v(float x) {
    float r;
    asm("v_exp_f32 %0, %1" : "=v"(r) : "v"(x));
    return r;
}
__device__ __forceinline__ u32 cvtpk(float lo, float hi) {
    u32 r;
    asm("v_cvt_pk_bf16_f32 %0, %1, %2" : "=v"(r) : "v"(lo), "v"(hi));
    return r;
}

#define GL16(gp, lp) __builtin_amdgcn_global_load_lds( \
    (const __attribute__((address_space(1))) u32*)(gp), \
    (__attribute__((address_space(3))) u32*)(lp), 16, 0, 0)

// ---------------------------------------------------------------------------
// fp32 -> bf16 convert (vectorized, 8 elems/thread)
__global__ __launch_bounds__(256) void f2bker(const float* __restrict__ in, u16* __restrict__ out) {
    size_t i = ((size_t)blockIdx.x * 256 + threadIdx.x) * 8;
    float4 a = *(const float4*)(in + i);
    float4 b = *(const float4*)(in + i + 4);
    u16x8 w;
    w[0] = f2bf(a.x); w[1] = f2bf(a.y); w[2] = f2bf(a.z); w[3] = f2bf(a.w);
    w[4] = f2bf(b.x); w[5] = f2bf(b.y); w[6] = f2bf(b.z); w[7] = f2bf(b.w);
    *(u16x8*)(out + i) = w;
}

// ---------------------------------------------------------------------------
// transpose + convert: in fp32 [R][C] -> out bf16 [C][R]  (64x64 tiles)
__global__ __launch_bounds__(256) void wtrans(const float* __restrict__ in, u16* __restrict__ out,
                                              int R, int C) {
    __shared__ u16 t[64 * 65];
    const int tid = threadIdx.x;
    const int c0 = blockIdx.x * 64, r0 = blockIdx.y * 64;
#pragma unroll
    for (int it = 0; it < 4; ++it) {
        int f = it * 256 + tid;
        int row = f >> 4, c4 = (f & 15) * 4;
        float4 v = *(const float4*)(in + (size_t)(r0 + row) * C + c0 + c4);
        t[row * 65 + c4 + 0] = f2bf(v.x);
        t[row * 65 + c4 + 1] = f2bf(v.y);
        t[row * 65 + c4 + 2] = f2bf(v.z);
        t[row * 65 + c4 + 3] = f2bf(v.w);
    }
    __syncthreads();
#pragma unroll
    for (int it = 0; it < 2; ++it) {
        int f = it * 256 + tid;
        int oc = f >> 3, r8 = (f & 7) * 8;
        u16x8 w;
#pragma unroll
        for (int j = 0; j < 8; ++j) w[j] = t[(r8 + j) * 65 + oc];
        *(u16x8*)(out + (size_t)(c0 + oc) * R + r0 + r8) = w;
    }
}

// ---------------------------------------------------------------------------
// RoPE table: tab[t][d2] = (cos(t*invf), sin(t*invf)), T=2048, 32 pairs
__global__ __launch_bounds__(256) void rope_tab(float2* __restrict__ tab) {
    int i = blockIdx.x * 256 + threadIdx.x;   // 65536
    int tpos = i >> 5, d2 = i & 31;
    float invf = powf(10000.f, -(float)(2 * d2) / 64.f);
    float fr = (float)tpos * invf;
    tab[i] = make_float2(cosf(fr), sinf(fr));
}

// RoPE in-place on Q or K (B,H,T,D) bf16; pair index i over all elems/2
__global__ __launch_bounds__(256) void rope_ip(u16* __restrict__ Q, u16* __restrict__ K,
                                               const float2* __restrict__ tab) {
    int i = blockIdx.x * 256 + threadIdx.x;   // 4,194,304 pairs
    u32* p = (u32*)(blockIdx.y ? K : Q) + i;
    int d2 = i & 31, tpos = (i >> 5) & 2047;
    float2 cs = tab[tpos * 32 + d2];
    u32 v = *p;
    float xe = bf2f((u16)(v & 0xffff));
    float xo = bf2f((u16)(v >> 16));
    float re = xe * cs.x - xo * cs.y;
    float ro = xe * cs.y + xo * cs.x;
    *p = (u32)f2bf(re) | ((u32)f2bf(ro) << 16);
}

// ---------------------------------------------------------------------------
// GEMM: C[MxN] = A[MxK](bf16,rowmajor) * Bt[NxK](bf16,rowmajor-as-B^T) + bias
// 128x128 tile, BK=32, 256 threads (2x2 waves, 64x64 each), m97 structure.
// MODE 0: fp32 out. MODE 1: scatter q,k to (B,H,T,D) bf16; v to (B,H,D,T).
template <int MODE>
__global__ __launch_bounds__(256, 2) void gemm_bt(
    const u16* __restrict__ A, const u16* __restrict__ Bt,
    const float* __restrict__ bias, float* __restrict__ Cf,
    u16* __restrict__ Qb, u16* __restrict__ Kb, u16* __restrict__ VbT,
    int M, int N, int K) {
    __shared__ __align__(16) u16 lsA[128 * 32];
    __shared__ __align__(16) u16 lsB[128 * 32];
    const int tid = threadIdx.x;
    const int wv = tid >> 6, lane = tid & 63;
    const int g = lane >> 4, c = lane & 15;
    const int m0 = blockIdx.y * 128, n0 = blockIdx.x * 128;
    const int wr = wv >> 1, wc = wv & 1;

    f32x4 acc[4][4] = {};

    const u16* gA = A + (size_t)(m0 + (tid >> 2)) * K + (tid & 3) * 8;
    const u16* gB = Bt + (size_t)(n0 + (tid >> 2)) * K + (tid & 3) * 8;
    const size_t rs64 = (size_t)64 * K;
    unsigned ldsW = (unsigned)__builtin_amdgcn_readfirstlane(wv * 1024);
    char* lA = (char*)lsA + ldsW;
    char* lB = (char*)lsB + ldsW;

    for (int k0 = 0; k0 < K; k0 += 32) {
        GL16(gA + k0, lA);
        GL16(gA + k0 + rs64, lA + 4096);
        GL16(gB + k0, lB);
        GL16(gB + k0 + rs64, lB + 4096);
        __syncthreads();
        bf16x8 af[4], bfr[4];
#pragma unroll
        for (int i = 0; i < 4; ++i)
            af[i] = *(const bf16x8*)(lsA + (wr * 64 + i * 16 + c) * 32 + g * 8);
#pragma unroll
        for (int j = 0; j < 4; ++j)
            bfr[j] = *(const bf16x8*)(lsB + (wc * 64 + j * 16 + c) * 32 + g * 8);
#pragma unroll
        for (int i = 0; i < 4; ++i)
#pragma unroll
            for (int j = 0; j < 4; ++j)
                acc[i][j] = __builtin_amdgcn_mfma_f32_16x16x32_bf16(af[i], bfr[j], acc[i][j], 0, 0, 0);
        __syncthreads();
    }

    if (MODE == 0) {
#pragma unroll
        for (int i = 0; i < 4; ++i)
#pragma unroll
            for (int r = 0; r < 4; ++r) {
                int m = m0 + wr * 64 + i * 16 + g * 4 + r;
#pragma unroll
                for (int j = 0; j < 4; ++j) {
                    int n = n0 + wc * 64 + j * 16 + c;
                    Cf[(size_t)m * N + n] = acc[i][j][r] + bias[n];
                }
            }
    } else {
        const int part = n0 >> 10;  // tile never crosses 1024-boundary
#pragma unroll
        for (int i = 0; i < 4; ++i)
#pragma unroll
            for (int r = 0; r < 4; ++r) {
                int m = m0 + wr * 64 + i * 16 + g * 4 + r;
                int b = m >> 11, t = m & 2047;
#pragma unroll
                for (int j = 0; j < 4; ++j) {
                    int n = n0 + wc * 64 + j * 16 + c;
                    int e = n & 1023, h = e >> 6, d = e & 63;
                    float v = acc[i][j][r] + bias[n];
                    u16 bv = f2bf(v);
                    if (part == 0)
                        Qb[(((size_t)b * 16 + h) * 2048 + t) * 64 + d] = bv;
                    else if (part == 1)
                        Kb[(((size_t)b * 16 + h) * 2048 + t) * 64 + d] = bv;
                    else
                        VbT[(((size_t)b * 16 + h) * 64 + d) * 2048 + t] = bv;
                }
            }
    }
}

// ---------------------------------------------------------------------------
// Flash attention, swapped-operand form. 1024 blocks, 256 threads
// (4 waves x 32 q each; block = 128 q rows). Per wave, per kv-tile (64):
//   S^T = mfma(A=K, B=Q) for two q-halves -> lane owns q=c / q=c+16
//   softmax in-lane (fold 0.125*log2e into FMA, raw v_exp_f32,
//   defer-rescale vote THR=8), P packed via v_cvt_pk_bf16_f32
//   O^T += mfma(A=V^T, B=P^T) -> alpha/l stay in-lane
// K/V double-buffered LDS (XOR swizzle), ONE barrier per tile, next tile's
// global loads issued right after the barrier (T14).
__global__ __launch_bounds__(256, 3) void attn_fwd(
    const u16* __restrict__ Qb, const u16* __restrict__ Kb,
    const u16* __restrict__ VbT, u16* __restrict__ Ob) {
    __shared__ __align__(16) u16 Kt[2][4096];   // [buf][kv=64][d=64] swizzled
    __shared__ __align__(16) u16 Vt[2][4096];   // [buf][d=64][kv=64] swizzled
    __shared__ __align__(16) u16 Pt[4][2048];   // per-wave [q=32][kv=64] swizzled
    const int tid = threadIdx.x, wv = tid >> 6, lane = tid & 63;
    const int g = lane >> 4, c = lane & 15;
    // XCD-clustered mapping: same bh -> same XCD; big blocks first
    const int bid = blockIdx.x;                 // 0..1023
    const int xcd = bid & 7, slot = bid >> 3;
    const int bh = (xcd << 3) | (slot >> 4);
    const int blk = 15 - (slot & 15);
    const int b = bh >> 4, h = bh & 15;
    const int q0 = blk * 128;
    const int q0w = q0 + wv * 32;
    const int qlo = q0w + c, qhi = q0w + 16 + c;
    const float CSC = 0.18033688011112042f;     // 0.125 * log2(e)

    // Q fragments (B-operand): Q[q][d = g*8 + i], two 32-wide d chunks, 2 halves
    const u16* qp = Qb + ((size_t)bh * 2048 + qlo) * 64 + g * 8;
    bf16x8 bq0l = *(const bf16x8*)(qp);
    bf16x8 bq1l = *(const bf16x8*)(qp + 32);
    bf16x8 bq0h = *(const bf16x8*)(qp + 16 * 64);
    bf16x8 bq1h = *(const bf16x8*)(qp + 16 * 64 + 32);

    float m_lo = -INFINITY, l_lo = 0.f;
    float m_hi = -INFINITY, l_hi = 0.f;
    f32x4 accL[4] = {}, accH[4] = {};

    const int stRow = tid >> 3;                 // 0..31
    const int stCol = (tid & 7) * 8;            // 0..56
    const u16* gK = Kb + (size_t)bh * 2048 * 64 + (size_t)stRow * 64 + stCol;
    const u16* gV = VbT + (size_t)bh * 64 * 2048 + (size_t)stRow * 2048 + stCol;
    const unsigned sw8 = (unsigned)(stRow & 7) << 4;
    const unsigned sAd0 = ((unsigned)(stRow * 128 + stCol * 2)) ^ sw8;
    const unsigned sAd1 = ((unsigned)((stRow + 32) * 128 + stCol * 2)) ^ sw8;
    const unsigned swz = (unsigned)(c & 7) << 4;
    char* pw = (char*)&Pt[wv][0];

    const int ktend = 2 * blk + 1;              // block's last tile
    const int ktmax_w = (q0w + 31) >> 6;        // wave's last compute tile

    // prologue: stage tile 0
    u16x8 kr0 = *(const u16x8*)(gK);
    u16x8 kr1 = *(const u16x8*)(gK + 32 * 64);
    u16x8 vr0 = *(const u16x8*)(gV);
    u16x8 vr1 = *(const u16x8*)(gV + 32 * 2048);
    *(u16x8*)((char*)Kt[0] + sAd0) = kr0;
    *(u16x8*)((char*)Kt[0] + sAd1) = kr1;
    *(u16x8*)((char*)Vt[0] + sAd0) = vr0;
    *(u16x8*)((char*)Vt[0] + sAd1) = vr1;
    int cur = 0;

    for (int kt = 0; kt <= ktend; ++kt) {
        __syncthreads();                        // buf[cur] ready for all waves
        if (kt < ktend) {                       // issue next tile early (T14)
            const u16* nK = gK + (size_t)(kt + 1) * 64 * 64;
            const u16* nV = gV + (size_t)(kt + 1) * 64;
            kr0 = *(const u16x8*)(nK);
            kr1 = *(const u16x8*)(nK + 32 * 64);
            vr0 = *(const u16x8*)(nV);
            vr1 = *(const u16x8*)(nV + 32 * 2048);
        }
        if (kt <= ktmax_w) {
            const char* Kc = (const char*)Kt[cur];
            const char* Vc = (const char*)Vt[cur];

            // S^T = K x Q^T : 4 kv-subtiles x 2 d-chunks x 2 q-halves
            f32x4 sl[4] = {}, sh[4] = {};
#pragma unroll
            for (int j = 0; j < 4; ++j) {
                unsigned rb = (unsigned)((16 * j + c) * 128 + g * 16);
                bf16x8 ka0 = *(const bf16x8*)(Kc + (rb ^ swz));
                bf16x8 ka1 = *(const bf16x8*)(Kc + ((rb + 64) ^ swz));
                sl[j] = __builtin_amdgcn_mfma_f32_16x16x32_bf16(ka0, bq0l, sl[j], 0, 0, 0);
                sl[j] = __builtin_amdgcn_mfma_f32_16x16x32_bf16(ka1, bq1l, sl[j], 0, 0, 0);
                sh[j] = __builtin_amdgcn_mfma_f32_16x16x32_bf16(ka0, bq0h, sh[j], 0, 0, 0);
                sh[j] = __builtin_amdgcn_mfma_f32_16x16x32_bf16(ka1, bq1h, sh[j], 0, 0, 0);
            }

            // causal mask (wave-uniform branches; only diag tiles pay)
            const int kvb = kt * 64 + 4 * g;
            if (kt * 64 + 63 > q0w) {
#pragma unroll
                for (int j = 0; j < 4; ++j)
#pragma unroll
                    for (int r = 0; r < 4; ++r)
                        if (kvb + 16 * j + r > qlo) sl[j][r] = -INFINITY;
            }
            if (kt * 64 + 63 > q0w + 16) {
#pragma unroll
                for (int j = 0; j < 4; ++j)
#pragma unroll
                    for (int r = 0; r < 4; ++r)
                        if (kvb + 16 * j + r > qhi) sh[j][r] = -INFINITY;
            }

            // online softmax per half: lane q=c(+16), kv = kt*64+16j+4g+r
#pragma unroll
            for (int half = 0; half < 2; ++half) {
                f32x4* s = half ? sh : sl;
                float& m_r = half ? m_hi : m_lo;
                float& l_r = half ? l_hi : l_lo;
                f32x4* acc = half ? accH : accL;
                float mx = -INFINITY;
#pragma unroll
                for (int j = 0; j < 4; ++j)
#pragma unroll
                    for (int r = 0; r < 4; ++r) mx = fmaxf(mx, s[j][r]);
                mx = fmaxf(mx, __shfl_xor(mx, 16));
                mx = fmaxf(mx, __shfl_xor(mx, 32));
                if (!__all((mx - m_r) * CSC <= 8.f)) {   // T13 defer-rescale
                    float mn = fmaxf(m_r, mx);
                    float al = exp2v((m_r - mn) * CSC);
                    l_r *= al;
#pragma unroll
                    for (int dj = 0; dj < 4; ++dj) acc[dj] *= al;
                    m_r = mn;
                }
                const float mc = m_r * CSC;
                float sum = 0.f;
                u32 pp[8];
#pragma unroll
                for (int j = 0; j < 4; ++j) {
#pragma unroll
                    for (int t2 = 0; t2 < 2; ++t2) {
                        float p0 = exp2v(fmaf(s[j][2 * t2], CSC, -mc));
                        float p1 = exp2v(fmaf(s[j][2 * t2 + 1], CSC, -mc));
                        sum += p0 + p1;
                        pp[j * 2 + t2] = cvtpk(p0, p1);
                    }
                }
                sum += __shfl_xor(sum, 16);
                sum += __shfl_xor(sum, 32);
                l_r += sum;
                // P -> per-wave LDS [q=32][kv] swizzled, same wave, no barrier
                unsigned rq = (unsigned)(c + 16 * half) * 128;
#pragma unroll
                for (int j = 0; j < 4; ++j) {
                    uint2 w2;
                    w2.x = pp[j * 2];
                    w2.y = pp[j * 2 + 1];
                    *(uint2*)(pw + ((rq + j * 32 + g * 8) ^ swz)) = w2;
                }
            }

            // O^T += V^T x P^T (V reads shared between halves)
#pragma unroll
            for (int ks = 0; ks < 2; ++ks) {
                bf16x8 pbl = *(const bf16x8*)(pw + ((unsigned)(c * 128 + ks * 64 + g * 16) ^ swz));
                bf16x8 pbh = *(const bf16x8*)(pw + ((unsigned)((c + 16) * 128 + ks * 64 + g * 16) ^ swz));
#pragma unroll
                for (int dj = 0; dj < 4; ++dj) {
                    unsigned vb = (unsigned)((dj * 16 + c) * 128 + ks * 64 + g * 16) ^ swz;
                    bf16x8 va = *(const bf16x8*)(Vc + vb);
                    accL[dj] = __builtin_amdgcn_mfma_f32_16x16x32_bf16(va, pbl, accL[dj], 0, 0, 0);
                    accH[dj] = __builtin_amdgcn_mfma_f32_16x16x32_bf16(va, pbh, accH[dj], 0, 0, 0);
                }
            }
        }

        // stage next tile into the other buffer (vmcnt drain lands here)
        if (kt < ktend) {
            int nb = cur ^ 1;
            *(u16x8*)((char*)Kt[nb] + sAd0) = kr0;
            *(u16x8*)((char*)Kt[nb] + sAd1) = kr1;
            *(u16x8*)((char*)Vt[nb] + sAd0) = vr0;
            *(u16x8*)((char*)Vt[nb] + sAd1) = vr1;
            cur = nb;
        }
    }

    // epilogue: O[q][d] = accO^T / l, bf16 pairs (8B per dj) per half
#pragma unroll
    for (int half = 0; half < 2; ++half) {
        const f32x4* acc = half ? accH : accL;
        float inv = 1.f / (half ? l_hi : l_lo);
        int q = half ? qhi : qlo;
        u16* ob = Ob + ((size_t)b * 2048 + q) * 1024 + h * 64;
#pragma unroll
        for (int dj = 0; dj < 4; ++dj) {
            f32x4 o = acc[dj] * inv;
            uint2 w;
            w.x = cvtpk(o[0], o[1]);
            w.y = cvtpk(o[2], o[3]);
            *(uint2*)(ob + dj * 16 + 4 * g) = w;
        }
    }
}

// ---------------------------------------------------------------------------
extern "C" void kernel_launch(void* const* d_in, const int* in_sizes, int n_in,
                              void* d_out, int out_size, void* d_ws, size_t ws_size,
                              hipStream_t stream) {
    const float* x = (const float*)d_in[0];
    const float* Wqkv = (const float*)d_in[1];
    const float* bqkv = (const float*)d_in[2];
    const float* Wproj = (const float*)d_in[3];
    const float* bproj = (const float*)d_in[4];
    float* out = (float*)d_out;

    char* ws = (char*)d_ws;
    u16* xb = (u16*)(ws);                       // 16,777,216 B; reused as Ob
    u16* WqkvT = (u16*)(ws + 16777216);         //  6,291,456 B
    u16* WprojT = (u16*)(ws + 23068672);        //  2,097,152 B
    u16* Qb = (u16*)(ws + 25165824);            // 16,777,216 B
    u16* Kb = (u16*)(ws + 41943040);            // 16,777,216 B
    u16* VbT = (u16*)(ws + 58720256);           // 16,777,216 B
    float2* tab = (float2*)(ws + 75497472);     //    524,288 B  (total ~76 MB)

    f2bker<<<4096, 256, 0, stream>>>(x, xb);
    wtrans<<<dim3(48, 16), 256, 0, stream>>>(Wqkv, WqkvT, 1024, 3072);
    wtrans<<<dim3(16, 16), 256, 0, stream>>>(Wproj, WprojT, 1024, 1024);
    rope_tab<<<256, 256, 0, stream>>>(tab);
    gemm_bt<1><<<dim3(24, 64), 256, 0, stream>>>(xb, WqkvT, bqkv, nullptr, Qb, Kb, VbT,
                                                 8192, 3072, 1024);
    rope_ip<<<dim3(16384, 2), 256, 0, stream>>>(Qb, Kb, tab);
    attn_fwd<<<1024, 256, 0, stream>>>(Qb, Kb, VbT, xb /*Ob*/);
    gemm_bt<0><<<dim3(8, 64), 256, 0, stream>>>(xb, WprojT, bproj, out,
                                                nullptr, nullptr, nullptr,
                                                8192, 1024, 1024);
}